// Round 13
// baseline (48.680 us; speedup 1.0000x reference)
//
#include <hip/hip_runtime.h>

#define KCLS 21
#define HW (512 * 512)
#define BATCH 8
#define NBLK 2048
#define BLKSZ 256
#define BPI (NBLK / BATCH)             // 256 blocks per image
#define PIXB (HW / BPI)                // 1024 px per block
#define ITERS (PIXB / BLKSZ)           // 4 px per thread, one at a time
#define NPAIR (BATCH * KCLS)           // 168

// ws layout (per-block partials, plain stores -> no memset node needed):
//   u32 ti[NBLK*21] (inter<<12 | tgt) | u32 ao[NBLK*21] | f32 S[NBLK*21]

__global__ __launch_bounds__(BLKSZ, 8) void dicece_histo(
    const float* __restrict__ pr, const int* __restrict__ gt,
    unsigned int* __restrict__ ws_ti, unsigned int* __restrict__ ws_ao,
    float* __restrict__ ws_S)
{
    __shared__ unsigned int s_ti[KCLS];    // inter<<12 | tgt (block counts <= 1024)
    __shared__ unsigned int s_aout[KCLS];
    __shared__ float s_S[KCLS];
    const int t = threadIdx.x;
    if (t < KCLS) { s_ti[t] = 0u; s_aout[t] = 0u; s_S[t] = 0.f; }
    __syncthreads();

    const int b = blockIdx.x / BPI;
    const int chunk = blockIdx.x - b * BPI;
    const float* __restrict__ pb = pr + (size_t)b * KCLS * HW + chunk * PIXB;
    const int*   __restrict__ gb = gt + (size_t)b * HW + chunk * PIXB;

    // R8-proven hot loop: 1 px/thread, 21 coalesced scalar dword streams.
    #pragma unroll 1
    for (int it = 0; it < ITERS; ++it) {
        const int p = it * BLKSZ + t;

        float x[KCLS];
        #pragma unroll
        for (int k = 0; k < KCLS; ++k) x[k] = pb[(size_t)k * HW + p];
        const int gj = gb[p];

        float m = x[0];
        int am = 0;
        #pragma unroll
        for (int k = 1; k < KCLS; ++k) {
            if (x[k] > m) { m = x[k]; am = k; }
        }
        float s = 0.f;
        #pragma unroll
        for (int k = 0; k < KCLS; ++k) s += __expf(x[k] - m);
        float xg = x[0];
        #pragma unroll
        for (int k = 1; k < KCLS; ++k) xg = (k == gj) ? x[k] : xg;
        const float logp = xg - m - __logf(s);

        atomicAdd(&s_ti[gj], (am == gj) ? ((1u << 12) | 1u) : 1u);
        atomicAdd(&s_aout[am], 1u);
        atomicAdd(&s_S[gj], logp);
    }
    __syncthreads();

    // per-block partial slots: plain stores, fully overwritten every call
    if (t < KCLS) {
        const size_t slot = (size_t)blockIdx.x * KCLS + t;
        ws_ti[slot] = s_ti[t];
        ws_ao[slot] = s_aout[t];
        ws_S [slot] = s_S[t];
    }
}

__global__ __launch_bounds__(1024) void dicece_final(
    const unsigned int* __restrict__ ws_ti, const unsigned int* __restrict__ ws_ao,
    const float* __restrict__ ws_S, float* __restrict__ out)
{
    __shared__ float l_i[4][NPAIR], l_t[4][NPAIR], l_a[4][NPAIR], l_s[4][NPAIR];
    __shared__ float f_dice[NPAIR], f_tg[NPAIR], f_S[NPAIR];
    const int t = threadIdx.x;
    const int slice = t >> 8;          // 0..3: each sums 64 of 256 blocks
    const int q = t & 255;             // pair index when < 168

    if (q < NPAIR) {
        const int bb = q / KCLS, kk = q - bb * KCLS;
        unsigned int pi = 0u, pt = 0u, pa = 0u;
        float ps = 0.f;
        const int blk0 = slice * (BPI / 4);
        #pragma unroll 4
        for (int blk = blk0; blk < blk0 + BPI / 4; ++blk) {
            const size_t slot = (size_t)(bb * BPI + blk) * KCLS + kk;
            const unsigned int ti = ws_ti[slot];
            pi += ti >> 12;
            pt += ti & 0xFFFu;
            pa += ws_ao[slot];
            ps += ws_S[slot];
        }
        l_i[slice][q] = (float)pi; l_t[slice][q] = (float)pt;
        l_a[slice][q] = (float)pa; l_s[slice][q] = ps;
    }
    __syncthreads();

    if (t < NPAIR) {
        const float i_ = l_i[0][t] + l_i[1][t] + l_i[2][t] + l_i[3][t];
        const float tg = l_t[0][t] + l_t[1][t] + l_t[2][t] + l_t[3][t];
        const float ao = l_a[0][t] + l_a[1][t] + l_a[2][t] + l_a[3][t];
        f_S[t]    = l_s[0][t] + l_s[1][t] + l_s[2][t] + l_s[3][t];
        f_dice[t] = 2.f * i_ / (ao + tg + 1e-10f);   // union+inter == ao+tgt
        f_tg[t]   = tg;
    }
    __syncthreads();
    if (t >= 64) return;

    float wgt = 0.f, Nk = 0.f, Sk = 0.f;
    if (t < KCLS) {
        float dsum = 0.f;
        #pragma unroll
        for (int bb = 0; bb < BATCH; ++bb) {
            dsum += f_dice[bb * KCLS + t];
            Nk   += f_tg[bb * KCLS + t];
            Sk   += f_S[bb * KCLS + t];      // sum of logp (negative) for class t
        }
        wgt = 1.f - dsum * 0.125f;           // weight = 1 - dice_class (SAMPLES=8)
    }
    float num = wgt * Sk, den = wgt * Nk, wsum = wgt;
    #pragma unroll
    for (int off = 32; off > 0; off >>= 1) {
        num  += __shfl_down(num, off);
        den  += __shfl_down(den, off);
        wsum += __shfl_down(wsum, off);
    }
    // loss = BETA * mean(weight) + celoss, celoss = -(sum w*logp)/(sum w*N)
    if (t == 0) out[0] = wsum * (1.f / (float)KCLS) - num / den;
}

extern "C" void kernel_launch(void* const* d_in, const int* in_sizes, int n_in,
                              void* d_out, int out_size, void* d_ws, size_t ws_size,
                              hipStream_t stream) {
    const float* pr = (const float*)d_in[0];
    const int*   gt = (const int*)d_in[1];
    float* out = (float*)d_out;

    unsigned int* ws_ti = (unsigned int*)d_ws;
    unsigned int* ws_ao = ws_ti + (size_t)NBLK * KCLS;
    float*        ws_S  = (float*)(ws_ao + (size_t)NBLK * KCLS);

    dicece_histo<<<NBLK, BLKSZ, 0, stream>>>(pr, gt, ws_ti, ws_ao, ws_S);
    dicece_final<<<1, 1024, 0, stream>>>(ws_ti, ws_ao, ws_S, out);
}

// Round 14
// 44.889 us; speedup vs baseline: 1.0845x; 1.0845x over previous
//
#include <hip/hip_runtime.h>

#define KCLS 21
#define HW (512 * 512)
#define BATCH 8
#define NBLK 2048
#define BLKSZ 256
#define BPI (NBLK / BATCH)             // 256 blocks per image
#define PIXB (HW / BPI)                // 1024 px per block
#define ITERS (PIXB / BLKSZ)           // 4 px per thread, one at a time

// ws layout: u32 inter[8*21] | u32 aout[8*21] | u32 atgt[8*21] | f32 S[8*21]

__global__ __launch_bounds__(BLKSZ, 8) void dicece_histo(
    const float* __restrict__ pr, const int* __restrict__ gt,
    unsigned int* __restrict__ ws_inter, unsigned int* __restrict__ ws_aout,
    unsigned int* __restrict__ ws_atgt, float* __restrict__ ws_S)
{
    __shared__ unsigned int s_ti[KCLS];    // inter<<12 | tgt (block counts <= 1024)
    __shared__ unsigned int s_aout[KCLS];
    __shared__ float s_S[KCLS];
    const int t = threadIdx.x;
    if (t < KCLS) { s_ti[t] = 0u; s_aout[t] = 0u; s_S[t] = 0.f; }
    __syncthreads();

    const int b = blockIdx.x / BPI;
    const int chunk = blockIdx.x - b * BPI;
    const float* __restrict__ pb = pr + (size_t)b * KCLS * HW + chunk * PIXB;
    const int*   __restrict__ gb = gt + (size_t)b * HW + chunk * PIXB;

    // one pixel per thread per iteration: 21 scalar dword streams,
    // 64 consecutive px per wave-instr (fully coalesced), small VGPR footprint.
    #pragma unroll 1
    for (int it = 0; it < ITERS; ++it) {
        const int p = it * BLKSZ + t;

        float x[KCLS];
        #pragma unroll
        for (int k = 0; k < KCLS; ++k) x[k] = pb[(size_t)k * HW + p];
        const int gj = gb[p];

        float m = x[0];
        int am = 0;
        #pragma unroll
        for (int k = 1; k < KCLS; ++k) {
            if (x[k] > m) { m = x[k]; am = k; }
        }
        float s = 0.f;
        #pragma unroll
        for (int k = 0; k < KCLS; ++k) s += __expf(x[k] - m);
        float xg = x[0];
        #pragma unroll
        for (int k = 1; k < KCLS; ++k) xg = (k == gj) ? x[k] : xg;
        const float logp = xg - m - __logf(s);

        // 3 LDS atomics/px, branch-free: tgt+inter packed
        atomicAdd(&s_ti[gj], (am == gj) ? ((1u << 12) | 1u) : 1u);
        atomicAdd(&s_aout[am], 1u);
        atomicAdd(&s_S[gj], logp);
    }
    __syncthreads();

    if (t < KCLS) {
        const unsigned int ti = s_ti[t];
        atomicAdd(&ws_inter[b * KCLS + t], ti >> 12);
        atomicAdd(&ws_atgt [b * KCLS + t], ti & 0xFFFu);
        atomicAdd(&ws_aout [b * KCLS + t], s_aout[t]);
        atomicAdd(&ws_S    [b * KCLS + t], s_S[t]);
    }
}

__global__ void dicece_final(
    const unsigned int* __restrict__ ws_inter, const unsigned int* __restrict__ ws_aout,
    const unsigned int* __restrict__ ws_atgt, const float* __restrict__ ws_S,
    float* __restrict__ out)
{
    const int k = threadIdx.x;   // one wave; lanes >= 21 contribute 0
    float w = 0.f, Nk = 0.f, Sk = 0.f;
    if (k < KCLS) {
        float dsum = 0.f;
        unsigned int nk = 0u;
        #pragma unroll
        for (int b = 0; b < BATCH; ++b) {
            const float inter = (float)ws_inter[b * KCLS + k];
            const float ao    = (float)ws_aout [b * KCLS + k];
            const float at    = (float)ws_atgt [b * KCLS + k];
            nk += ws_atgt[b * KCLS + k];
            dsum += 2.f * inter / (ao + at + 1e-10f);   // union+inter == ao+at
            Sk += ws_S[b * KCLS + k];
        }
        w  = 1.f - dsum * 0.125f;   // weight = 1 - dice_class (SAMPLES=8)
        Nk = (float)nk;
    }
    float num = w * Sk, den = w * Nk, wsum = w;
    #pragma unroll
    for (int off = 32; off > 0; off >>= 1) {
        num  += __shfl_down(num, off);
        den  += __shfl_down(den, off);
        wsum += __shfl_down(wsum, off);
    }
    // BETA * mean(weight) + (-(sum w*logp) / (sum w*N))
    if (k == 0) out[0] = wsum / (float)KCLS - num / den;
}

extern "C" void kernel_launch(void* const* d_in, const int* in_sizes, int n_in,
                              void* d_out, int out_size, void* d_ws, size_t ws_size,
                              hipStream_t stream) {
    const float* pr = (const float*)d_in[0];
    const int*   gt = (const int*)d_in[1];
    float* out = (float*)d_out;

    unsigned int* ws_inter = (unsigned int*)d_ws;
    unsigned int* ws_aout  = ws_inter + BATCH * KCLS;
    unsigned int* ws_atgt  = ws_aout  + BATCH * KCLS;
    float*        ws_S     = (float*)(ws_atgt + BATCH * KCLS);

    hipMemsetAsync(d_ws, 0, (size_t)(4 * BATCH * KCLS) * sizeof(float), stream);
    dicece_histo<<<NBLK, BLKSZ, 0, stream>>>(pr, gt, ws_inter, ws_aout, ws_atgt, ws_S);
    dicece_final<<<1, 64, 0, stream>>>(ws_inter, ws_aout, ws_atgt, ws_S, out);
}